// Round 1
// 677.659 us; speedup vs baseline: 1.0898x; 1.0898x over previous
//
#include <hip/hip_runtime.h>
#include <stdint.h>
#include <algorithm>

// Sparse conv encoder on MI355X. R6 rewrite: per-layer gather-GEMM with the
// 9 kernel offsets FLATTENED into the GEMM K dimension (K = 9*CIN, BK=64).
// Block = 256 rows x 128 couts, 512 threads (8 waves, wave tile 64x64),
// v_mfma_f32_16x16x32_bf16. Double-buffered LDS, ONE barrier per K-step,
// next-step staging issued before current MFMA (T3-minimum schedule).
// bf16 paths stage via global_load_lds (16B) with source-side XOR swizzle
// (seg ^= row&7) so ds_read_b128 is bank-conflict-free; invalid gathers load
// a zero page via branchless address select (divergence would corrupt the
// wave-uniform LDS dest). fp32-input layers (c1/c2 reading fp32 outputs)
// reg-stage with issue-early/pack-late (T14). Optional ws tiers let d0/d1
// dual-write bf16 copies so c1/c2 use the pure gload path.
// Previous structure: 2 barriers/k + serial gather+pack -> MfmaUtil 11.8%,
// 195us top dispatch. Prediction: ~30% MfmaUtil, ~60-80us.

#define DI __device__ __forceinline__

typedef __attribute__((ext_vector_type(8))) short bf16x8;
typedef __attribute__((ext_vector_type(4))) float f32x4;

DI uint16_t f2bf(float x){
  union{float f;uint32_t i;}v; v.f=x;
  uint32_t r = v.i + 0x7fffu + ((v.i>>16)&1u);
  return (uint16_t)(r>>16);
}
DI uint32_t pack2(float a, float b){
  return (uint32_t)f2bf(a) | ((uint32_t)f2bf(b) << 16);
}
DI void gload16(const void* g, void* l){
  __builtin_amdgcn_global_load_lds(
      (const __attribute__((address_space(1))) void*)g,
      (__attribute__((address_space(3))) void*)l, 16, 0, 0);
}

__global__ __launch_bounds__(256) void diag_kernel(float* __restrict__ out, long n, float c){
  long i = (long)blockIdx.x*256 + threadIdx.x;
  if (i < n) out[i] = c;
}

__global__ __launch_bounds__(256) void init_table_kernel(int* __restrict__ t, long n){
  long i = (long)blockIdx.x*256 + threadIdx.x;
  if (i < n) t[i] = -1;
}

__global__ __launch_bounds__(256) void build_table_kernel(
    const int* __restrict__ im, const int* __restrict__ om,
    int* __restrict__ tab, int M, int n_in, int n_out){
  const int k = blockIdx.y;
  long t = (long)blockIdx.x*256 + threadIdx.x;
  if (t >= M) return;
  int ii = im[(long)k*M + t];
  int oo = om[(long)k*M + t];
  if (ii >= 0 && ii < n_in && oo >= 0 && oo < n_out)
    tab[(long)k*n_out + oo] = ii;
}

// w (9,cin,128) fp32 -> wtb (9,128,cin) bf16 (cout-major rows = B operand rows).
__global__ __launch_bounds__(256) void prep_w_kernel(
    const float* __restrict__ w, uint16_t* __restrict__ wtb, int cin){
  long idx = (long)blockIdx.x*256 + threadIdx.x;
  long total = 9L*128*cin;
  if (idx >= total) return;
  int k = (int)(idx / (128*cin));
  int rem = (int)(idx % (128*cin));
  int cout = rem / cin, ci = rem % cin;
  wtb[idx] = f2bf(w[((long)k*cin + ci)*128 + cout]);
}

// c0 (1->64 ch) via table: thread = row; 9 table reads + 9 cached gathers + FMA.
__global__ __launch_bounds__(256) void c0_tab_kernel(
    const float* __restrict__ feats, const float* __restrict__ w,
    const float* __restrict__ bias, const int* __restrict__ tab,
    uint16_t* __restrict__ out, int n_out){
  __shared__ float w_s[576];
  __shared__ float b_s[64];
  const int tid = threadIdx.x;
  for (int i = tid; i < 576; i += 256) w_s[i] = w[i];
  if (tid < 64) b_s[tid] = bias[tid];
  __syncthreads();
  long r = (long)blockIdx.x*256 + tid;
  if (r >= n_out) return;
  float f[9];
  #pragma unroll
  for (int k = 0; k < 9; k++){
    int gi = tab[(long)k*n_out + r];
    f[k] = (gi >= 0) ? feats[gi] : 0.f;
  }
  uint16_t* dst = out + r*64;
  #pragma unroll
  for (int c0 = 0; c0 < 64; c0 += 16){
    float a[16];
    #pragma unroll
    for (int j = 0; j < 16; j++) a[j] = b_s[c0+j];
    #pragma unroll
    for (int k = 0; k < 9; k++){
      float fk = f[k];
      #pragma unroll
      for (int j = 0; j < 16; j++) a[j] += fk * w_s[k*64 + c0 + j];
    }
    uint4 o0, o1;
    o0.x = pack2(a[0],a[1]);   o0.y = pack2(a[2],a[3]);
    o0.z = pack2(a[4],a[5]);   o0.w = pack2(a[6],a[7]);
    o1.x = pack2(a[8],a[9]);   o1.y = pack2(a[10],a[11]);
    o1.z = pack2(a[12],a[13]); o1.w = pack2(a[14],a[15]);
    *(uint4*)(dst + c0)     = o0;
    *(uint4*)(dst + c0 + 8) = o1;
  }
}

// Flattened-K gathered GEMM.
// INMODE: 0 = bf16 [n_in][CIN] via global_load_lds; 1 = fp32 [n_in][128] reg-staged.
// OUTMODE: 0 = fp32 only; 1 = bf16 only; 2 = both.
template<int CIN, int INMODE, int OUTMODE, bool RELU>
__global__ __launch_bounds__(512,2) void mconv2_kernel(
    const void* __restrict__ in_v, const uint16_t* __restrict__ wtb,
    const float* __restrict__ bias, const int* __restrict__ tab,
    const uint16_t* __restrict__ zp,
    float* __restrict__ outf, uint16_t* __restrict__ outb, int n_out){
  constexpr int NS = 9*CIN/64;                 // K-steps of 64
  __shared__ __align__(16) uint16_t ab[2][256*64];   // A: 256 rows x BK, 2 bufs
  __shared__ __align__(16) uint16_t bb[2][128*64];   // B: 128 couts x BK, 2 bufs
  __shared__ int gi_sh[9*256];

  const int tid = threadIdx.x;
  // bijective XCD-chunked swizzle (m204) for gather L2 locality
  const int nwg = gridDim.x, orig = blockIdx.x;
  const int q = nwg >> 3, rr = nwg & 7, xcd = orig & 7, pos = orig >> 3;
  const int wg = (xcd < rr ? xcd*(q+1) : rr*(q+1) + (xcd-rr)*q) + pos;
  const long rb = (long)wg * 256;

  for (int idx = tid; idx < 9*256; idx += 512){
    int k = idx >> 8, r = idx & 255;
    long row = rb + r;
    gi_sh[idx] = (row < (long)n_out) ? tab[(long)k*n_out + row] : -1;
  }
  __syncthreads();

  const int lane = tid & 63;
  const int wv = tid >> 6;
  const int wr = (wv >> 1) << 6;    // row wave: 0,64,128,192
  const int wc = (wv & 1) << 6;     // col wave: 0,64
  const int l16 = lane & 15, quad = lane >> 4;

  f32x4 acc[4][4];
  #pragma unroll
  for (int i = 0; i < 4; i++)
    #pragma unroll
    for (int j = 0; j < 4; j++)
      acc[i][j] = (f32x4){0.f,0.f,0.f,0.f};

  // weights: always bf16 gload. Source pre-swizzled: phys seg sg holds logical
  // seg sg^(row&7) -> read side applies the same XOR (bank-conflict-free).
  auto stage_b = [&](int step, int nb){
    const int kk = (CIN == 64) ? step : (step >> 1);
    const int ci0 = (CIN == 64) ? 0 : ((step & 1) << 6);
    #pragma unroll
    for (int it = 0; it < 2; ++it){
      int slot = it*512 + tid;
      int co = slot >> 3, sg = slot & 7;
      int ss = sg ^ (co & 7);
      gload16(wtb + ((long)kk*128 + co)*CIN + ci0 + ss*8, &bb[nb][slot*8]);
    }
  };
  auto stage_a_bf = [&](int step, int nb){
    const int kk = (CIN == 64) ? step : (step >> 1);
    const int ci0 = (CIN == 64) ? 0 : ((step & 1) << 6);
    const uint16_t* fb = (const uint16_t*)in_v;
    #pragma unroll
    for (int it = 0; it < 4; ++it){
      int slot = it*512 + tid;
      int r = slot >> 3, sg = slot & 7;
      int gi = gi_sh[(kk << 8) + r];
      int ss = sg ^ (r & 7);
      // branchless select: divergence around gload_lds would shift the
      // wave-uniform LDS base (first-active-lane semantics) -> corruption.
      long sel = -(long)(gi >= 0);
      long pv = (long)(uintptr_t)(fb + (long)gi*CIN + ci0 + ss*8);
      long pz = (long)(uintptr_t)(zp + ss*8);
      const void* src = (const void*)(uintptr_t)((pv & sel) | (pz & ~sel));
      gload16(src, &ab[nb][slot*8]);
    }
  };
  auto stage_a_f32_issue = [&](int step, float4 (*va)[2]){
    const int kk = step >> 1;
    const int ci0 = (step & 1) << 6;
    const float* fb = (const float*)in_v;
    #pragma unroll
    for (int it = 0; it < 4; ++it){
      int slot = it*512 + tid;
      int r = slot >> 3, sg = slot & 7;
      int gi = gi_sh[(kk << 8) + r];
      int ss = sg ^ (r & 7);
      if (gi >= 0){
        const float4* s = (const float4*)(fb + (long)gi*128 + ci0 + ss*8);
        va[it][0] = s[0]; va[it][1] = s[1];
      } else {
        va[it][0] = make_float4(0.f,0.f,0.f,0.f);
        va[it][1] = make_float4(0.f,0.f,0.f,0.f);
      }
    }
  };
  auto stage_a_f32_write = [&](float4 (*va)[2], int nb){
    #pragma unroll
    for (int it = 0; it < 4; ++it){
      int slot = it*512 + tid;
      uint4 o;
      o.x = pack2(va[it][0].x, va[it][0].y);
      o.y = pack2(va[it][0].z, va[it][0].w);
      o.z = pack2(va[it][1].x, va[it][1].y);
      o.w = pack2(va[it][1].z, va[it][1].w);
      *(uint4*)&ab[nb][slot*8] = o;
    }
  };
  auto compute = [&](int nb){
    const uint16_t* A  = &ab[nb][0];
    const uint16_t* Bm = &bb[nb][0];
    #pragma unroll
    for (int ch = 0; ch < 2; ++ch){
      // row&7 == l16&7 for every fragment row (wr,wc,u*16 are 0 mod 8)
      const int xs = ((((ch << 2) + quad) ^ (l16 & 7)) << 3);
      bf16x8 af[4], bfr[4];
      #pragma unroll
      for (int u = 0; u < 4; ++u){
        af[u]  = *(const bf16x8*)&A [((wr + (u<<4) + l16) << 6) + xs];
        bfr[u] = *(const bf16x8*)&Bm[((wc + (u<<4) + l16) << 6) + xs];
      }
      #pragma unroll
      for (int rt = 0; rt < 4; ++rt)
        #pragma unroll
        for (int ct = 0; ct < 4; ++ct)
          acc[rt][ct] = __builtin_amdgcn_mfma_f32_16x16x32_bf16(
              af[rt], bfr[ct], acc[rt][ct], 0, 0, 0);
    }
  };

  float4 va[4][2];
  if constexpr (INMODE == 0){
    stage_a_bf(0, 0);
  } else {
    stage_a_f32_issue(0, va);
    stage_a_f32_write(va, 0);
  }
  stage_b(0, 0);
  __syncthreads();

  int cur = 0;
  for (int t = 0; t < NS; ++t){
    const bool more = (t + 1 < NS);
    if (more){
      if constexpr (INMODE == 0) stage_a_bf(t+1, cur^1);
      else stage_a_f32_issue(t+1, va);
      stage_b(t+1, cur^1);
    }
    compute(cur);
    if constexpr (INMODE != 0){
      if (more) stage_a_f32_write(va, cur^1);   // T14: pack+write after MFMA
    }
    if (more) __syncthreads();   // drains vmcnt/lgkm: next bufs ready
    cur ^= 1;
  }

  // C/D mapping (verified): col = l16, row = quad*4 + r
  #pragma unroll
  for (int ct = 0; ct < 4; ++ct){
    const int cout = wc + (ct<<4) + l16;
    const float bv = bias[cout];
    #pragma unroll
    for (int rt = 0; rt < 4; ++rt){
      #pragma unroll
      for (int r = 0; r < 4; ++r){
        long row = rb + wr + (rt<<4) + (quad<<2) + r;
        if (row < (long)n_out){
          float v = acc[rt][ct][r] + bv;
          if (RELU) v = v > 0.f ? v : 0.f;
          if constexpr (OUTMODE == 0 || OUTMODE == 2) outf[row*128 + cout] = v;
          if constexpr (OUTMODE == 1 || OUTMODE == 2) outb[row*128 + cout] = f2bf(v);
        }
      }
    }
  }
}

static inline long cdivl(long a, long b){ return (a + b - 1) / b; }

extern "C" void kernel_launch(void* const* d_in, const int* in_sizes, int n_in_args,
                              void* d_out, int out_size, void* d_ws, size_t ws_size,
                              hipStream_t stream) {
  const float* feats = (const float*)d_in[0];
  const float* w_c0 = (const float*)d_in[1];
  const float* b_c0 = (const float*)d_in[2];
  const int* in_c0  = (const int*)d_in[3];
  const int* out_c0 = (const int*)d_in[4];
  const float* w_d0 = (const float*)d_in[5];
  const float* b_d0 = (const float*)d_in[6];
  const int* in_d0  = (const int*)d_in[7];
  const int* out_d0 = (const int*)d_in[8];
  const float* w_c1 = (const float*)d_in[9];
  const float* b_c1 = (const float*)d_in[10];
  const int* in_c1  = (const int*)d_in[11];
  const int* out_c1 = (const int*)d_in[12];
  const float* w_d1 = (const float*)d_in[13];
  const float* b_d1 = (const float*)d_in[14];
  const int* in_d1  = (const int*)d_in[15];
  const int* out_d1 = (const int*)d_in[16];
  const float* w_c2 = (const float*)d_in[17];
  const float* b_c2 = (const float*)d_in[18];
  const int* in_c2  = (const int*)d_in[19];
  const int* out_c2 = (const int*)d_in[20];
  const float* w_d2 = (const float*)d_in[21];
  const float* b_d2 = (const float*)d_in[22];
  const int* in_d2  = (const int*)d_in[23];
  const int* out_d2 = (const int*)d_in[24];

  const int n0   = in_sizes[0];
  const int M_c0 = in_sizes[3]  / 9;
  const int M_d0 = in_sizes[7]  / 9;
  const int M_c1 = in_sizes[11] / 9;
  const int M_d1 = in_sizes[15] / 9;
  const int M_c2 = in_sizes[19] / 9;
  const int M_d2 = in_sizes[23] / 9;
  const int n1   = M_c1;
  const int n2   = M_c2;
  const int n3   = out_size/128 - n1 - n2;

  bool sane = n0 > 0 && out_size % 128 == 0 &&
              M_c0 > 0 && M_d0 > 0 && M_d1 > 0 && M_d2 > 0 &&
              n1 > 0 && n2 > 0 && n3 > 0;

  long maxElems = (long)n0*64;
  if ((long)n1*128 > maxElems) maxElems = (long)n1*128;
  if ((long)n2*128 > maxElems) maxElems = (long)n2*128;
  long fbytes = (maxElems*2 + 255)/256*256;
  long tbytes = (9L*n0*4 + 255)/256*256;
  long wt64  = 9L*128*64, wt128 = 9L*128*128;
  long wbytes = ((wt64 + 4*wt128)*2 + 255)/256*256;
  long zbytes = 256;
  long b1bytes = sane ? ((long)n2*128*2 + 255)/256*256 : 0;
  long b0bytes = sane ? ((long)n1*128*2 + 255)/256*256 : 0;
  long need0 = fbytes + tbytes + wbytes + zbytes + 256;

  if (!sane || ws_size < (size_t)need0){
    float C = (float)(16 + (int)std::min<size_t>(ws_size >> 20, (size_t)100000));
    if (!sane) C *= 1099511627776.0f;
    diag_kernel<<<cdivl(out_size,256),256,0,stream>>>((float*)d_out, out_size, C);
    return;
  }

  // ws: [ fbuf | table | wtb x5 | zero page | bf1 (tier1) | bf0 (tier2) ]
  uint16_t* fbuf = (uint16_t*)d_ws;
  int* table = (int*)((char*)d_ws + fbytes);
  uint16_t* wtb_d0 = (uint16_t*)((char*)d_ws + fbytes + tbytes);
  uint16_t* wtb_c1 = wtb_d0 + wt64;
  uint16_t* wtb_d1 = wtb_c1 + wt128;
  uint16_t* wtb_c2 = wtb_d1 + wt128;
  uint16_t* wtb_d2 = wtb_c2 + wt128;
  uint16_t* zp  = (uint16_t*)((char*)d_ws + fbytes + tbytes + wbytes);
  uint16_t* bf1 = (uint16_t*)((char*)d_ws + need0);
  uint16_t* bf0 = (uint16_t*)((char*)d_ws + need0 + b1bytes);
  int tier = 0;
  if (ws_size >= (size_t)(need0 + b1bytes)) tier = 1;
  if (ws_size >= (size_t)(need0 + b1bytes + b0bytes)) tier = 2;

  float* out2 = (float*)d_out;
  float* out1 = out2 + (long)n3*128;
  float* out0 = out1 + (long)n2*128;

  // weight transposes + zero page
  prep_w_kernel<<<cdivl(9L*128*64,256),256,0,stream>>>(w_d0, wtb_d0, 64);
  prep_w_kernel<<<cdivl(9L*128*128,256),256,0,stream>>>(w_c1, wtb_c1, 128);
  prep_w_kernel<<<cdivl(9L*128*128,256),256,0,stream>>>(w_d1, wtb_d1, 128);
  prep_w_kernel<<<cdivl(9L*128*128,256),256,0,stream>>>(w_c2, wtb_c2, 128);
  prep_w_kernel<<<cdivl(9L*128*128,256),256,0,stream>>>(w_d2, wtb_d2, 128);
  diag_kernel<<<1,256,0,stream>>>((float*)zp, 64, 0.0f);

  auto make_tab = [&](const int* im, const int* om, int M, int nin, int nout){
    long n = 9L*nout;
    init_table_kernel<<<cdivl(n,256),256,0,stream>>>(table, n);
    dim3 g((unsigned)cdivl(M,256), 9);
    build_table_kernel<<<g,256,0,stream>>>(im, om, table, M, nin, nout);
  };

  // c0: feats fp32 -> fbuf(x) bf16 [n0][64]
  make_tab(in_c0, out_c0, M_c0, n0, n0);
  c0_tab_kernel<<<cdivl(n0,256),256,0,stream>>>(feats, w_c0, b_c0, table, fbuf, n0);

  // d0: x bf16 -> out0 fp32 (+ bf0 bf16 at tier2), relu
  make_tab(in_d0, out_d0, M_d0, n0, n1);
  if (tier >= 2)
    mconv2_kernel<64,0,2,true><<<cdivl(n1,256),512,0,stream>>>(
        fbuf, wtb_d0, b_d0, table, zp, out0, bf0, n1);
  else
    mconv2_kernel<64,0,0,true><<<cdivl(n1,256),512,0,stream>>>(
        fbuf, wtb_d0, b_d0, table, zp, out0, nullptr, n1);

  // c1: (bf0 bf16 | out0 fp32) -> fbuf(y) bf16
  make_tab(in_c1, out_c1, M_c1, n1, n1);
  if (tier >= 2)
    mconv2_kernel<128,0,1,false><<<cdivl(n1,256),512,0,stream>>>(
        bf0, wtb_c1, b_c1, table, zp, nullptr, fbuf, n1);
  else
    mconv2_kernel<128,1,1,false><<<cdivl(n1,256),512,0,stream>>>(
        out0, wtb_c1, b_c1, table, zp, nullptr, fbuf, n1);

  // d1: y bf16 -> out1 fp32 (+ bf1 bf16 at tier1), relu
  make_tab(in_d1, out_d1, M_d1, n1, n2);
  if (tier >= 1)
    mconv2_kernel<128,0,2,true><<<cdivl(n2,256),512,0,stream>>>(
        fbuf, wtb_d1, b_d1, table, zp, out1, bf1, n2);
  else
    mconv2_kernel<128,0,0,true><<<cdivl(n2,256),512,0,stream>>>(
        fbuf, wtb_d1, b_d1, table, zp, out1, nullptr, n2);

  // c2: (bf1 bf16 | out1 fp32) -> fbuf(z) bf16
  make_tab(in_c2, out_c2, M_c2, n2, n2);
  if (tier >= 1)
    mconv2_kernel<128,0,1,false><<<cdivl(n2,256),512,0,stream>>>(
        bf1, wtb_c2, b_c2, table, zp, nullptr, fbuf, n2);
  else
    mconv2_kernel<128,1,1,false><<<cdivl(n2,256),512,0,stream>>>(
        out1, wtb_c2, b_c2, table, zp, nullptr, fbuf, n2);

  // d2: z bf16 -> out2 fp32
  make_tab(in_d2, out_d2, M_d2, n2, n3);
  mconv2_kernel<128,0,0,false><<<cdivl(n3,256),512,0,stream>>>(
      fbuf, wtb_d2, b_d2, table, zp, out2, nullptr, n3);
}

// Round 2
// 574.035 us; speedup vs baseline: 1.2866x; 1.1805x over previous
//
#include <hip/hip_runtime.h>
#include <stdint.h>
#include <algorithm>

// Sparse conv encoder on MI355X. R7: occupancy + address-precompute pass.
// R6 analysis: LDS 105KB -> 1 block/CU (Occ 21.9%), per-K-step ~5300cy vs
// ~300cy compute -> gather-latency bound with depth-1 overlap. R7: BM=128
// (LDS 65.5KB -> 2 blocks/CU, 16 waves), gather addresses precomputed into
// 18 uint32 ws-relative register offsets (prologue branchless zero-page
// select; main loop fully unrolled so offA[][] indexing is static), gi_sh
// LDS reads + 64b addr math gone from the hot loop. s_setprio(1) around the
// MFMA cluster (2 independent blocks/CU -> role diversity, T5).
// Kept from R6 (verified): flattened-K gather-GEMM (K=9*CIN, BK=64),
// global_load_lds 16B with source-side XOR swizzle (zero bank conflicts),
// double-buffered LDS, one barrier per step, bijective XCD chunk swizzle.
// Predict: Occ ~43%, top dispatch 119 -> ~55-70us, total 678 -> ~450us.

#define DI __device__ __forceinline__

typedef __attribute__((ext_vector_type(8))) short bf16x8;
typedef __attribute__((ext_vector_type(4))) float f32x4;

DI uint16_t f2bf(float x){
  union{float f;uint32_t i;}v; v.f=x;
  uint32_t r = v.i + 0x7fffu + ((v.i>>16)&1u);
  return (uint16_t)(r>>16);
}
DI uint32_t pack2(float a, float b){
  return (uint32_t)f2bf(a) | ((uint32_t)f2bf(b) << 16);
}
DI void gload16(const void* g, void* l){
  __builtin_amdgcn_global_load_lds(
      (const __attribute__((address_space(1))) void*)g,
      (__attribute__((address_space(3))) void*)l, 16, 0, 0);
}

__global__ __launch_bounds__(256) void diag_kernel(float* __restrict__ out, long n, float c){
  long i = (long)blockIdx.x*256 + threadIdx.x;
  if (i < n) out[i] = c;
}

__global__ __launch_bounds__(256) void init_table_kernel(int* __restrict__ t, long n){
  long i = (long)blockIdx.x*256 + threadIdx.x;
  if (i < n) t[i] = -1;
}

__global__ __launch_bounds__(256) void build_table_kernel(
    const int* __restrict__ im, const int* __restrict__ om,
    int* __restrict__ tab, int M, int n_in, int n_out){
  const int k = blockIdx.y;
  long t = (long)blockIdx.x*256 + threadIdx.x;
  if (t >= M) return;
  int ii = im[(long)k*M + t];
  int oo = om[(long)k*M + t];
  if (ii >= 0 && ii < n_in && oo >= 0 && oo < n_out)
    tab[(long)k*n_out + oo] = ii;
}

// w (9,cin,128) fp32 -> wtb (9,128,cin) bf16 (cout-major rows = B operand rows).
__global__ __launch_bounds__(256) void prep_w_kernel(
    const float* __restrict__ w, uint16_t* __restrict__ wtb, int cin){
  long idx = (long)blockIdx.x*256 + threadIdx.x;
  long total = 9L*128*cin;
  if (idx >= total) return;
  int k = (int)(idx / (128*cin));
  int rem = (int)(idx % (128*cin));
  int cout = rem / cin, ci = rem % cin;
  wtb[idx] = f2bf(w[((long)k*cin + ci)*128 + cout]);
}

// c0 (1->64 ch) via table: thread = row; 9 table reads + 9 cached gathers + FMA.
__global__ __launch_bounds__(256) void c0_tab_kernel(
    const float* __restrict__ feats, const float* __restrict__ w,
    const float* __restrict__ bias, const int* __restrict__ tab,
    uint16_t* __restrict__ out, int n_out){
  __shared__ float w_s[576];
  __shared__ float b_s[64];
  const int tid = threadIdx.x;
  for (int i = tid; i < 576; i += 256) w_s[i] = w[i];
  if (tid < 64) b_s[tid] = bias[tid];
  __syncthreads();
  long r = (long)blockIdx.x*256 + tid;
  if (r >= n_out) return;
  float f[9];
  #pragma unroll
  for (int k = 0; k < 9; k++){
    int gi = tab[(long)k*n_out + r];
    f[k] = (gi >= 0) ? feats[gi] : 0.f;
  }
  uint16_t* dst = out + r*64;
  #pragma unroll
  for (int c0 = 0; c0 < 64; c0 += 16){
    float a[16];
    #pragma unroll
    for (int j = 0; j < 16; j++) a[j] = b_s[c0+j];
    #pragma unroll
    for (int k = 0; k < 9; k++){
      float fk = f[k];
      #pragma unroll
      for (int j = 0; j < 16; j++) a[j] += fk * w_s[k*64 + c0 + j];
    }
    uint4 o0, o1;
    o0.x = pack2(a[0],a[1]);   o0.y = pack2(a[2],a[3]);
    o0.z = pack2(a[4],a[5]);   o0.w = pack2(a[6],a[7]);
    o1.x = pack2(a[8],a[9]);   o1.y = pack2(a[10],a[11]);
    o1.z = pack2(a[12],a[13]); o1.w = pack2(a[14],a[15]);
    *(uint4*)(dst + c0)     = o0;
    *(uint4*)(dst + c0 + 8) = o1;
  }
}

// Flattened-K gathered GEMM, BM=128 x BN=128, BK=64, 512 thr (8 waves 4x2,
// wave tile 32x64), 2 blocks/CU.
// INMODE: 0 = bf16 in ws via global_load_lds + reg-precomputed offsets;
//         1 = fp32 [n_in][128] via in_v, reg-staged (T14).
// OUTMODE: 0 = fp32 only; 1 = bf16 only; 2 = both.
template<int CIN, int INMODE, int OUTMODE, bool RELU>
__global__ __launch_bounds__(512,4) void mconv2_kernel(
    const void* __restrict__ in_v, const char* __restrict__ ws_base,
    long in_off, long wtb_off, long zp_off,
    const float* __restrict__ bias, const int* __restrict__ tab,
    float* __restrict__ outf, uint16_t* __restrict__ outb, int n_out){
  constexpr int NS = 9*CIN/64;                       // K-steps of 64
  __shared__ __align__(16) uint16_t ab[2][128*64];   // A: 128 rows x BK
  __shared__ __align__(16) uint16_t bb[2][128*64];   // B: 128 couts x BK
  __shared__ int gi_sh[(INMODE==1) ? 9*128 : 1];

  const int tid = threadIdx.x;
  // bijective XCD-chunked swizzle (m204) for gather L2 locality
  const int nwg = gridDim.x, orig = blockIdx.x;
  const int q = nwg >> 3, rr = nwg & 7, xcd = orig & 7, pos = orig >> 3;
  const int wg = (xcd < rr ? xcd*(q+1) : rr*(q+1) + (xcd-rr)*q) + pos;
  const long rb = (long)wg * 128;

  const int r0 = tid >> 3, sg = tid & 7;
  const int ss0 = sg ^ (r0 & 7);       // r1=r0+64 -> same &7 -> same swizzle

  // A gather offsets: ws-relative uint32, zero-page select done ONCE here.
  uint32_t offA[2][9];
  if constexpr (INMODE == 0){
    #pragma unroll
    for (int kk = 0; kk < 9; ++kk){
      #pragma unroll
      for (int it = 0; it < 2; ++it){
        long row = rb + it*64 + r0;
        int gi = (row < (long)n_out) ? tab[(long)kk*n_out + row] : -1;
        offA[it][kk] = (gi >= 0)
            ? (uint32_t)(in_off + (long)gi*(CIN*2) + ss0*16)
            : (uint32_t)(zp_off + ss0*16);
      }
    }
  } else {
    for (int idx = tid; idx < 9*128; idx += 512){
      int k = idx >> 7, r = idx & 127;
      long row = rb + r;
      gi_sh[idx] = (row < (long)n_out) ? tab[(long)k*n_out + row] : -1;
    }
    __syncthreads();
  }

  // B offsets: thread's cout rows co0, co0+64; same &7 -> same swizzle.
  const uint32_t offB = (uint32_t)(wtb_off + ((long)r0*CIN + ss0*8)*2);

  const int lane = tid & 63;
  const int wv = tid >> 6;
  const int wr = (wv >> 1) << 5;    // 4 row-waves x 32
  const int wc = (wv & 1) << 6;     // 2 col-waves x 64
  const int l16 = lane & 15, quad = lane >> 4;

  f32x4 acc[2][4];
  #pragma unroll
  for (int i = 0; i < 2; i++)
    #pragma unroll
    for (int j = 0; j < 4; j++)
      acc[i][j] = (f32x4){0.f,0.f,0.f,0.f};

  auto stage_b = [&](int step, int nb){
    const int kk  = (CIN == 64) ? step : (step >> 1);
    const int c0b = (CIN == 64) ? 0 : ((step & 1) * 128);
    const uint32_t base = offB + (uint32_t)((long)kk*128*CIN*2 + c0b);
    #pragma unroll
    for (int it = 0; it < 2; ++it)
      gload16(ws_base + base + it*(64*CIN*2), &bb[nb][(it*512+tid)*8]);
  };
  auto stage_a_bf = [&](int step, int nb){
    const int kk  = (CIN == 64) ? step : (step >> 1);
    const int c0b = (CIN == 64) ? 0 : ((step & 1) * 128);
    #pragma unroll
    for (int it = 0; it < 2; ++it)
      gload16(ws_base + offA[it][kk] + c0b, &ab[nb][(it*512+tid)*8]);
  };
  auto stage_a_f32_issue = [&](int step, float4 (*va)[2]){
    const int kk = step >> 1;
    const int ci0 = (step & 1) << 6;
    const float* fb = (const float*)in_v;
    #pragma unroll
    for (int it = 0; it < 2; ++it){
      int gi = gi_sh[(kk << 7) + it*64 + r0];
      if (gi >= 0){
        const float4* s = (const float4*)(fb + (long)gi*128 + ci0 + ss0*8);
        va[it][0] = s[0]; va[it][1] = s[1];
      } else {
        va[it][0] = make_float4(0.f,0.f,0.f,0.f);
        va[it][1] = make_float4(0.f,0.f,0.f,0.f);
      }
    }
  };
  auto stage_a_f32_write = [&](float4 (*va)[2], int nb){
    #pragma unroll
    for (int it = 0; it < 2; ++it){
      uint4 o;
      o.x = pack2(va[it][0].x, va[it][0].y);
      o.y = pack2(va[it][0].z, va[it][0].w);
      o.z = pack2(va[it][1].x, va[it][1].y);
      o.w = pack2(va[it][1].z, va[it][1].w);
      *(uint4*)&ab[nb][(it*512+tid)*8] = o;
    }
  };
  auto compute = [&](int nb){
    const uint16_t* A  = &ab[nb][0];
    const uint16_t* Bm = &bb[nb][0];
    __builtin_amdgcn_s_setprio(1);
    #pragma unroll
    for (int ch = 0; ch < 2; ++ch){
      // row&7 == l16&7 for every fragment row (wr,wc,u*16 are 0 mod 8)
      const int xs = ((((ch << 2) + quad) ^ (l16 & 7)) << 3);
      bf16x8 af[2], bfr[4];
      #pragma unroll
      for (int u = 0; u < 2; ++u)
        af[u]  = *(const bf16x8*)&A [((wr + (u<<4) + l16) << 6) + xs];
      #pragma unroll
      for (int u = 0; u < 4; ++u)
        bfr[u] = *(const bf16x8*)&Bm[((wc + (u<<4) + l16) << 6) + xs];
      #pragma unroll
      for (int rt = 0; rt < 2; ++rt)
        #pragma unroll
        for (int ct = 0; ct < 4; ++ct)
          acc[rt][ct] = __builtin_amdgcn_mfma_f32_16x16x32_bf16(
              af[rt], bfr[ct], acc[rt][ct], 0, 0, 0);
    }
    __builtin_amdgcn_s_setprio(0);
  };

  float4 va[2][2];
  if constexpr (INMODE == 0){
    stage_a_bf(0, 0);
  } else {
    stage_a_f32_issue(0, va);
    stage_a_f32_write(va, 0);
  }
  stage_b(0, 0);
  __syncthreads();

  #pragma unroll
  for (int t = 0; t < NS; ++t){
    const int cur = t & 1;
    const bool more = (t + 1 < NS);
    if (more){
      if constexpr (INMODE == 0) stage_a_bf(t+1, cur^1);
      else stage_a_f32_issue(t+1, va);
      stage_b(t+1, cur^1);
    }
    compute(cur);
    if constexpr (INMODE != 0){
      if (more) stage_a_f32_write(va, cur^1);   // T14: pack+write after MFMA
    }
    if (more) __syncthreads();   // drains vmcnt/lgkm: next bufs ready
  }

  // C/D mapping (verified): col = l16, row = quad*4 + r
  #pragma unroll
  for (int ct = 0; ct < 4; ++ct){
    const int cout = wc + (ct<<4) + l16;
    const float bv = bias[cout];
    #pragma unroll
    for (int rt = 0; rt < 2; ++rt){
      #pragma unroll
      for (int r = 0; r < 4; ++r){
        long row = rb + wr + (rt<<4) + (quad<<2) + r;
        if (row < (long)n_out){
          float v = acc[rt][ct][r] + bv;
          if (RELU) v = v > 0.f ? v : 0.f;
          if constexpr (OUTMODE == 0 || OUTMODE == 2) outf[row*128 + cout] = v;
          if constexpr (OUTMODE == 1 || OUTMODE == 2) outb[row*128 + cout] = f2bf(v);
        }
      }
    }
  }
}

static inline long cdivl(long a, long b){ return (a + b - 1) / b; }

extern "C" void kernel_launch(void* const* d_in, const int* in_sizes, int n_in_args,
                              void* d_out, int out_size, void* d_ws, size_t ws_size,
                              hipStream_t stream) {
  const float* feats = (const float*)d_in[0];
  const float* w_c0 = (const float*)d_in[1];
  const float* b_c0 = (const float*)d_in[2];
  const int* in_c0  = (const int*)d_in[3];
  const int* out_c0 = (const int*)d_in[4];
  const float* w_d0 = (const float*)d_in[5];
  const float* b_d0 = (const float*)d_in[6];
  const int* in_d0  = (const int*)d_in[7];
  const int* out_d0 = (const int*)d_in[8];
  const float* w_c1 = (const float*)d_in[9];
  const float* b_c1 = (const float*)d_in[10];
  const int* in_c1  = (const int*)d_in[11];
  const int* out_c1 = (const int*)d_in[12];
  const float* w_d1 = (const float*)d_in[13];
  const float* b_d1 = (const float*)d_in[14];
  const int* in_d1  = (const int*)d_in[15];
  const int* out_d1 = (const int*)d_in[16];
  const float* w_c2 = (const float*)d_in[17];
  const float* b_c2 = (const float*)d_in[18];
  const int* in_c2  = (const int*)d_in[19];
  const int* out_c2 = (const int*)d_in[20];
  const float* w_d2 = (const float*)d_in[21];
  const float* b_d2 = (const float*)d_in[22];
  const int* in_d2  = (const int*)d_in[23];
  const int* out_d2 = (const int*)d_in[24];

  const int n0   = in_sizes[0];
  const int M_c0 = in_sizes[3]  / 9;
  const int M_d0 = in_sizes[7]  / 9;
  const int M_c1 = in_sizes[11] / 9;
  const int M_d1 = in_sizes[15] / 9;
  const int M_c2 = in_sizes[19] / 9;
  const int M_d2 = in_sizes[23] / 9;
  const int n1   = M_c1;
  const int n2   = M_c2;
  const int n3   = out_size/128 - n1 - n2;

  bool sane = n0 > 0 && out_size % 128 == 0 &&
              M_c0 > 0 && M_d0 > 0 && M_d1 > 0 && M_d2 > 0 &&
              n1 > 0 && n2 > 0 && n3 > 0;

  long maxElems = (long)n0*64;
  if ((long)n1*128 > maxElems) maxElems = (long)n1*128;
  if ((long)n2*128 > maxElems) maxElems = (long)n2*128;
  long fbytes = (maxElems*2 + 255)/256*256;
  long tbytes = (9L*n0*4 + 255)/256*256;
  long wt64  = 9L*128*64, wt128 = 9L*128*128;
  long wbytes = ((wt64 + 4*wt128)*2 + 255)/256*256;
  long zbytes = 256;
  long b1bytes = sane ? ((long)n2*128*2 + 255)/256*256 : 0;
  long b0bytes = sane ? ((long)n1*128*2 + 255)/256*256 : 0;
  long need0 = fbytes + tbytes + wbytes + zbytes + 256;

  if (!sane || ws_size < (size_t)need0){
    float C = (float)(16 + (int)std::min<size_t>(ws_size >> 20, (size_t)100000));
    if (!sane) C *= 1099511627776.0f;
    diag_kernel<<<cdivl(out_size,256),256,0,stream>>>((float*)d_out, out_size, C);
    return;
  }

  // ws: [ fbuf | table | wtb x5 | zero page | bf1 (tier1) | bf0 (tier2) ]
  uint16_t* fbuf = (uint16_t*)d_ws;
  int* table = (int*)((char*)d_ws + fbytes);
  long wtb_d0_off = fbytes + tbytes;
  long wtb_c1_off = wtb_d0_off + wt64*2;
  long wtb_d1_off = wtb_c1_off + wt128*2;
  long wtb_c2_off = wtb_d1_off + wt128*2;
  long wtb_d2_off = wtb_c2_off + wt128*2;
  long zp_off     = fbytes + tbytes + wbytes;
  long bf1_off    = need0;
  long bf0_off    = need0 + b1bytes;
  const char* wsb = (const char*)d_ws;
  uint16_t* zp_p  = (uint16_t*)((char*)d_ws + zp_off);
  uint16_t* bf1   = (uint16_t*)((char*)d_ws + bf1_off);
  uint16_t* bf0   = (uint16_t*)((char*)d_ws + bf0_off);
  int tier = 0;
  if (ws_size >= (size_t)(need0 + b1bytes)) tier = 1;
  if (ws_size >= (size_t)(need0 + b1bytes + b0bytes)) tier = 2;

  float* out2 = (float*)d_out;
  float* out1 = out2 + (long)n3*128;
  float* out0 = out1 + (long)n2*128;

  // weight transposes + zero page
  prep_w_kernel<<<cdivl(9L*128*64,256),256,0,stream>>>(w_d0, (uint16_t*)((char*)d_ws + wtb_d0_off), 64);
  prep_w_kernel<<<cdivl(9L*128*128,256),256,0,stream>>>(w_c1, (uint16_t*)((char*)d_ws + wtb_c1_off), 128);
  prep_w_kernel<<<cdivl(9L*128*128,256),256,0,stream>>>(w_d1, (uint16_t*)((char*)d_ws + wtb_d1_off), 128);
  prep_w_kernel<<<cdivl(9L*128*128,256),256,0,stream>>>(w_c2, (uint16_t*)((char*)d_ws + wtb_c2_off), 128);
  prep_w_kernel<<<cdivl(9L*128*128,256),256,0,stream>>>(w_d2, (uint16_t*)((char*)d_ws + wtb_d2_off), 128);
  diag_kernel<<<1,256,0,stream>>>((float*)zp_p, 64, 0.0f);

  auto make_tab = [&](const int* im, const int* om, int M, int nin, int nout){
    long n = 9L*nout;
    init_table_kernel<<<cdivl(n,256),256,0,stream>>>(table, n);
    dim3 g((unsigned)cdivl(M,256), 9);
    build_table_kernel<<<g,256,0,stream>>>(im, om, table, M, nin, nout);
  };

  // c0: feats fp32 -> fbuf(x) bf16 [n0][64]
  make_tab(in_c0, out_c0, M_c0, n0, n0);
  c0_tab_kernel<<<cdivl(n0,256),256,0,stream>>>(feats, w_c0, b_c0, table, fbuf, n0);

  // d0: x bf16 -> out0 fp32 (+ bf0 bf16 at tier2), relu
  make_tab(in_d0, out_d0, M_d0, n0, n1);
  if (tier >= 2)
    mconv2_kernel<64,0,2,true><<<cdivl(n1,128),512,0,stream>>>(
        nullptr, wsb, 0L, wtb_d0_off, zp_off, b_d0, table, out0, bf0, n1);
  else
    mconv2_kernel<64,0,0,true><<<cdivl(n1,128),512,0,stream>>>(
        nullptr, wsb, 0L, wtb_d0_off, zp_off, b_d0, table, out0, nullptr, n1);

  // c1: (bf0 bf16 | out0 fp32) -> fbuf(y) bf16
  make_tab(in_c1, out_c1, M_c1, n1, n1);
  if (tier >= 2)
    mconv2_kernel<128,0,1,false><<<cdivl(n1,128),512,0,stream>>>(
        nullptr, wsb, bf0_off, wtb_c1_off, zp_off, b_c1, table, nullptr, fbuf, n1);
  else
    mconv2_kernel<128,1,1,false><<<cdivl(n1,128),512,0,stream>>>(
        out0, wsb, 0L, wtb_c1_off, zp_off, b_c1, table, nullptr, fbuf, n1);

  // d1: y bf16 -> out1 fp32 (+ bf1 bf16 at tier1), relu
  make_tab(in_d1, out_d1, M_d1, n1, n2);
  if (tier >= 1)
    mconv2_kernel<128,0,2,true><<<cdivl(n2,128),512,0,stream>>>(
        nullptr, wsb, 0L, wtb_d1_off, zp_off, b_d1, table, out1, bf1, n2);
  else
    mconv2_kernel<128,0,0,true><<<cdivl(n2,128),512,0,stream>>>(
        nullptr, wsb, 0L, wtb_d1_off, zp_off, b_d1, table, out1, nullptr, n2);

  // c2: (bf1 bf16 | out1 fp32) -> fbuf(z) bf16
  make_tab(in_c2, out_c2, M_c2, n2, n2);
  if (tier >= 1)
    mconv2_kernel<128,0,1,false><<<cdivl(n2,128),512,0,stream>>>(
        nullptr, wsb, bf1_off, wtb_c2_off, zp_off, b_c2, table, nullptr, fbuf, n2);
  else
    mconv2_kernel<128,1,1,false><<<cdivl(n2,128),512,0,stream>>>(
        out1, wsb, 0L, wtb_c2_off, zp_off, b_c2, table, nullptr, fbuf, n2);

  // d2: z bf16 -> out2 fp32
  make_tab(in_d2, out_d2, M_d2, n2, n3);
  mconv2_kernel<128,0,0,false><<<cdivl(n3,128),512,0,stream>>>(
      nullptr, wsb, 0L, wtb_d2_off, zp_off, b_d2, table, out2, nullptr, n3);
}

// Round 3
// 486.718 us; speedup vs baseline: 1.5174x; 1.1794x over previous
//
#include <hip/hip_runtime.h>
#include <stdint.h>
#include <algorithm>

// Sparse conv encoder on MI355X. R8: dispatch consolidation + T4 counted vmcnt.
// R7 analysis: mconvs all <107us (below harness-fill visibility) but total 574
// vs ~200us modeled work -> ~26 serialized dispatches at ~5-10us each are the
// gap. R8a: 26 -> 9 dispatches (one init_all for all 6 tables + zero page, one
// build_all with grid.z=6, one prep_all for 5 weight transposes). R8b: mconv
// K-loop __syncthreads (vmcnt(0) drain = zero-cover wait on just-issued loads)
// replaced with m218's counted pattern: issue next (4 VMEM/wave), s_waitcnt
// vmcnt(4) (current step's loads only, one compute-phase of cover),
// sched_barrier(0), s_barrier, MFMA, trailing s_barrier (WAR on buffer).
// Bias preloaded to regs so loop has exactly 4 VMEM instr/wave/step.
// Kept (verified R6/R7): flattened-K gather GEMM, gload_lds 16B, source-side
// XOR swizzle (0 bank conflicts), reg-precomputed gather offsets, BM=128
// (2 blocks/CU), XCD chunk swizzle, setprio around MFMA.
// Predict: 574 -> ~380-430us.

#define DI __device__ __forceinline__

typedef __attribute__((ext_vector_type(8))) short bf16x8;
typedef __attribute__((ext_vector_type(4))) float f32x4;

DI uint16_t f2bf(float x){
  union{float f;uint32_t i;}v; v.f=x;
  uint32_t r = v.i + 0x7fffu + ((v.i>>16)&1u);
  return (uint16_t)(r>>16);
}
DI uint32_t pack2(float a, float b){
  return (uint32_t)f2bf(a) | ((uint32_t)f2bf(b) << 16);
}
DI void gload16(const void* g, void* l){
  __builtin_amdgcn_global_load_lds(
      (const __attribute__((address_space(1))) void*)g,
      (__attribute__((address_space(3))) void*)l, 16, 0, 0);
}

__global__ __launch_bounds__(256) void diag_kernel(float* __restrict__ out, long n, float c){
  long i = (long)blockIdx.x*256 + threadIdx.x;
  if (i < n) out[i] = c;
}

// fill all tables with -1 + zero the 256B zero page, one dispatch
__global__ __launch_bounds__(256) void init_all_kernel(
    int* __restrict__ tab, long ntab, float* __restrict__ zp){
  long i = (long)blockIdx.x*256 + threadIdx.x;
  if (i < ntab) tab[i] = -1;
  if (blockIdx.x == 0 && threadIdx.x < 64) zp[threadIdx.x] = 0.f;
}

struct BuildArgs {
  const int* im[6];
  const int* om[6];
  int   M[6];
  int   nin[6];
  int   nout[6];
  long  toff[6];   // int offsets into table base
};

// all 6 layers' inverse tables, one dispatch (z = layer, y = offset k)
__global__ __launch_bounds__(256) void build_all_kernel(
    BuildArgs a, int* __restrict__ tb){
  const int L = blockIdx.z, k = blockIdx.y;
  const int M = a.M[L];
  long t = (long)blockIdx.x*256 + threadIdx.x;
  if (t >= M) return;
  int ii = a.im[L][(long)k*M + t];
  int oo = a.om[L][(long)k*M + t];
  if (ii >= 0 && ii < a.nin[L] && oo >= 0 && oo < a.nout[L])
    tb[a.toff[L] + (long)k*a.nout[L] + oo] = ii;
}

// all 5 weight transposes (9,cin,128) fp32 -> (9,128,cin) bf16, one dispatch.
// wtb region is contiguous: [d0 | c1 | d1 | c2 | d2], dst elem == idx.
__global__ __launch_bounds__(256) void prep_all_kernel(
    const float* __restrict__ w0, const float* __restrict__ w1,
    const float* __restrict__ w2, const float* __restrict__ w3,
    const float* __restrict__ w4, uint16_t* __restrict__ wb, long total){
  const long wt64 = 9L*128*64, wt128 = 9L*128*128;
  long idx = (long)blockIdx.x*256 + threadIdx.x;
  if (idx >= total) return;
  int L; long r; int cin;
  if (idx < wt64){ L = 0; r = idx; cin = 64; }
  else { long j = idx - wt64; L = 1 + (int)(j / wt128); r = j % wt128; cin = 128; }
  const float* w = (L==0) ? w0 : (L==1) ? w1 : (L==2) ? w2 : (L==3) ? w3 : w4;
  int k = (int)(r / (128*cin));
  int rem = (int)(r % (128*cin));
  int cout = rem / cin, ci = rem % cin;
  wb[idx] = f2bf(w[((long)k*cin + ci)*128 + cout]);
}

// c0 (1->64 ch) via table: thread = row; 9 table reads + 9 cached gathers + FMA.
__global__ __launch_bounds__(256) void c0_tab_kernel(
    const float* __restrict__ feats, const float* __restrict__ w,
    const float* __restrict__ bias, const int* __restrict__ tab,
    uint16_t* __restrict__ out, int n_out){
  __shared__ float w_s[576];
  __shared__ float b_s[64];
  const int tid = threadIdx.x;
  for (int i = tid; i < 576; i += 256) w_s[i] = w[i];
  if (tid < 64) b_s[tid] = bias[tid];
  __syncthreads();
  long r = (long)blockIdx.x*256 + tid;
  if (r >= n_out) return;
  float f[9];
  #pragma unroll
  for (int k = 0; k < 9; k++){
    int gi = tab[(long)k*n_out + r];
    f[k] = (gi >= 0) ? feats[gi] : 0.f;
  }
  uint16_t* dst = out + r*64;
  #pragma unroll
  for (int c0 = 0; c0 < 64; c0 += 16){
    float a[16];
    #pragma unroll
    for (int j = 0; j < 16; j++) a[j] = b_s[c0+j];
    #pragma unroll
    for (int k = 0; k < 9; k++){
      float fk = f[k];
      #pragma unroll
      for (int j = 0; j < 16; j++) a[j] += fk * w_s[k*64 + c0 + j];
    }
    uint4 o0, o1;
    o0.x = pack2(a[0],a[1]);   o0.y = pack2(a[2],a[3]);
    o0.z = pack2(a[4],a[5]);   o0.w = pack2(a[6],a[7]);
    o1.x = pack2(a[8],a[9]);   o1.y = pack2(a[10],a[11]);
    o1.z = pack2(a[12],a[13]); o1.w = pack2(a[14],a[15]);
    *(uint4*)(dst + c0)     = o0;
    *(uint4*)(dst + c0 + 8) = o1;
  }
}

// Flattened-K gathered GEMM, BM=128 x BN=128, BK=64, 512 thr (8 waves 4x2,
// wave tile 32x64), 2 blocks/CU.
// INMODE: 0 = bf16 in ws via global_load_lds + reg-precomputed offsets,
//             counted-vmcnt pipeline (T4);
//         1 = fp32 [n_in][128] via in_v, reg-staged (T14, fallback).
// OUTMODE: 0 = fp32 only; 1 = bf16 only; 2 = both.
template<int CIN, int INMODE, int OUTMODE, bool RELU>
__global__ __launch_bounds__(512,4) void mconv2_kernel(
    const void* __restrict__ in_v, const char* __restrict__ ws_base,
    long in_off, long wtb_off, long zp_off,
    const float* __restrict__ bias, const int* __restrict__ tab,
    float* __restrict__ outf, uint16_t* __restrict__ outb, int n_out){
  constexpr int NS = 9*CIN/64;                       // K-steps of 64
  __shared__ __align__(16) uint16_t ab[2][128*64];   // A: 128 rows x BK
  __shared__ __align__(16) uint16_t bb[2][128*64];   // B: 128 couts x BK
  __shared__ int gi_sh[(INMODE==1) ? 9*128 : 1];

  const int tid = threadIdx.x;
  // bijective XCD-chunked swizzle (m204) for gather L2 locality
  const int nwg = gridDim.x, orig = blockIdx.x;
  const int q = nwg >> 3, rr = nwg & 7, xcd = orig & 7, pos = orig >> 3;
  const int wg = (xcd < rr ? xcd*(q+1) : rr*(q+1) + (xcd-rr)*q) + pos;
  const long rb = (long)wg * 128;

  const int r0 = tid >> 3, sg = tid & 7;
  const int ss0 = sg ^ (r0 & 7);       // r1=r0+64 -> same &7 -> same swizzle

  // A gather offsets: ws-relative uint32, zero-page select done ONCE here.
  uint32_t offA[2][9];
  if constexpr (INMODE == 0){
    #pragma unroll
    for (int kk = 0; kk < 9; ++kk){
      #pragma unroll
      for (int it = 0; it < 2; ++it){
        long row = rb + it*64 + r0;
        int gi = (row < (long)n_out) ? tab[(long)kk*n_out + row] : -1;
        offA[it][kk] = (gi >= 0)
            ? (uint32_t)(in_off + (long)gi*(CIN*2) + ss0*16)
            : (uint32_t)(zp_off + ss0*16);
      }
    }
  } else {
    for (int idx = tid; idx < 9*128; idx += 512){
      int k = idx >> 7, r = idx & 127;
      long row = rb + r;
      gi_sh[idx] = (row < (long)n_out) ? tab[(long)k*n_out + row] : -1;
    }
    __syncthreads();
  }

  const uint32_t offB = (uint32_t)(wtb_off + ((long)r0*CIN + ss0*8)*2);

  const int lane = tid & 63;
  const int wv = tid >> 6;
  const int wr = (wv >> 1) << 5;    // 4 row-waves x 32
  const int wc = (wv & 1) << 6;     // 2 col-waves x 64
  const int l16 = lane & 15, quad = lane >> 4;

  // preload bias so the K-loop has exactly 4 VMEM instrs/wave/step
  float bv[4];
  #pragma unroll
  for (int ct = 0; ct < 4; ++ct) bv[ct] = bias[wc + (ct<<4) + l16];

  f32x4 acc[2][4];
  #pragma unroll
  for (int i = 0; i < 2; i++)
    #pragma unroll
    for (int j = 0; j < 4; j++)
      acc[i][j] = (f32x4){0.f,0.f,0.f,0.f};

  auto stage_b = [&](int step, int nb){
    const int kk  = (CIN == 64) ? step : (step >> 1);
    const int c0b = (CIN == 64) ? 0 : ((step & 1) * 128);
    const uint32_t base = offB + (uint32_t)((long)kk*128*CIN*2 + c0b);
    #pragma unroll
    for (int it = 0; it < 2; ++it)
      gload16(ws_base + base + it*(64*CIN*2), &bb[nb][(it*512+tid)*8]);
  };
  auto stage_a_bf = [&](int step, int nb){
    const int kk  = (CIN == 64) ? step : (step >> 1);
    const int c0b = (CIN == 64) ? 0 : ((step & 1) * 128);
    #pragma unroll
    for (int it = 0; it < 2; ++it)
      gload16(ws_base + offA[it][kk] + c0b, &ab[nb][(it*512+tid)*8]);
  };
  auto stage_a_f32_issue = [&](int step, float4 (*va)[2]){
    const int kk = step >> 1;
    const int ci0 = (step & 1) << 6;
    const float* fb = (const float*)in_v;
    #pragma unroll
    for (int it = 0; it < 2; ++it){
      int gi = gi_sh[(kk << 7) + it*64 + r0];
      if (gi >= 0){
        const float4* s = (const float4*)(fb + (long)gi*128 + ci0 + ss0*8);
        va[it][0] = s[0]; va[it][1] = s[1];
      } else {
        va[it][0] = make_float4(0.f,0.f,0.f,0.f);
        va[it][1] = make_float4(0.f,0.f,0.f,0.f);
      }
    }
  };
  auto stage_a_f32_write = [&](float4 (*va)[2], int nb){
    #pragma unroll
    for (int it = 0; it < 2; ++it){
      uint4 o;
      o.x = pack2(va[it][0].x, va[it][0].y);
      o.y = pack2(va[it][0].z, va[it][0].w);
      o.z = pack2(va[it][1].x, va[it][1].y);
      o.w = pack2(va[it][1].z, va[it][1].w);
      *(uint4*)&ab[nb][(it*512+tid)*8] = o;
    }
  };
  auto compute = [&](int nb){
    const uint16_t* A  = &ab[nb][0];
    const uint16_t* Bm = &bb[nb][0];
    __builtin_amdgcn_s_setprio(1);
    #pragma unroll
    for (int ch = 0; ch < 2; ++ch){
      // row&7 == l16&7 for every fragment row (wr,wc,u*16 are 0 mod 8)
      const int xs = ((((ch << 2) + quad) ^ (l16 & 7)) << 3);
      bf16x8 af[2], bfr[4];
      #pragma unroll
      for (int u = 0; u < 2; ++u)
        af[u]  = *(const bf16x8*)&A [((wr + (u<<4) + l16) << 6) + xs];
      #pragma unroll
      for (int u = 0; u < 4; ++u)
        bfr[u] = *(const bf16x8*)&Bm[((wc + (u<<4) + l16) << 6) + xs];
      #pragma unroll
      for (int rt = 0; rt < 2; ++rt)
        #pragma unroll
        for (int ct = 0; ct < 4; ++ct)
          acc[rt][ct] = __builtin_amdgcn_mfma_f32_16x16x32_bf16(
              af[rt], bfr[ct], acc[rt][ct], 0, 0, 0);
    }
    __builtin_amdgcn_s_setprio(0);
  };

  if constexpr (INMODE == 0){
    // T4 counted-vmcnt pipeline: loads for step t+1 stay in flight across
    // compute(t); each wave waits only for its 4 oldest (= step t's) loads.
    stage_a_bf(0, 0);
    stage_b(0, 0);
    #pragma unroll
    for (int t = 0; t < NS; ++t){
      const int cur = t & 1;
      if (t + 1 < NS){
        stage_a_bf(t+1, cur^1);
        stage_b(t+1, cur^1);
        asm volatile("s_waitcnt vmcnt(4)" ::: "memory");
      } else {
        asm volatile("s_waitcnt vmcnt(0)" ::: "memory");
      }
      __builtin_amdgcn_sched_barrier(0);
      __builtin_amdgcn_s_barrier();     // all waves' step-t data landed
      compute(cur);
      if (t + 1 < NS)
        __builtin_amdgcn_s_barrier();   // WAR: buffer cur free for step t+2
    }
  } else {
    float4 va[2][2];
    stage_a_f32_issue(0, va);
    stage_a_f32_write(va, 0);
    stage_b(0, 0);
    __syncthreads();
    #pragma unroll
    for (int t = 0; t < NS; ++t){
      const int cur = t & 1;
      const bool more = (t + 1 < NS);
      if (more){
        stage_a_f32_issue(t+1, va);
        stage_b(t+1, cur^1);
      }
      compute(cur);
      if (more){
        stage_a_f32_write(va, cur^1);   // T14: pack+write after MFMA
        __syncthreads();
      }
    }
  }

  // C/D mapping (verified): col = l16, row = quad*4 + r
  #pragma unroll
  for (int ct = 0; ct < 4; ++ct){
    const int cout = wc + (ct<<4) + l16;
    #pragma unroll
    for (int rt = 0; rt < 2; ++rt){
      #pragma unroll
      for (int r = 0; r < 4; ++r){
        long row = rb + wr + (rt<<4) + (quad<<2) + r;
        if (row < (long)n_out){
          float v = acc[rt][ct][r] + bv[ct];
          if (RELU) v = v > 0.f ? v : 0.f;
          if constexpr (OUTMODE == 0 || OUTMODE == 2) outf[row*128 + cout] = v;
          if constexpr (OUTMODE == 1 || OUTMODE == 2) outb[row*128 + cout] = f2bf(v);
        }
      }
    }
  }
}

static inline long cdivl(long a, long b){ return (a + b - 1) / b; }

extern "C" void kernel_launch(void* const* d_in, const int* in_sizes, int n_in_args,
                              void* d_out, int out_size, void* d_ws, size_t ws_size,
                              hipStream_t stream) {
  const float* feats = (const float*)d_in[0];
  const float* w_c0 = (const float*)d_in[1];
  const float* b_c0 = (const float*)d_in[2];
  const int* in_c0  = (const int*)d_in[3];
  const int* out_c0 = (const int*)d_in[4];
  const float* w_d0 = (const float*)d_in[5];
  const float* b_d0 = (const float*)d_in[6];
  const int* in_d0  = (const int*)d_in[7];
  const int* out_d0 = (const int*)d_in[8];
  const float* w_c1 = (const float*)d_in[9];
  const float* b_c1 = (const float*)d_in[10];
  const int* in_c1  = (const int*)d_in[11];
  const int* out_c1 = (const int*)d_in[12];
  const float* w_d1 = (const float*)d_in[13];
  const float* b_d1 = (const float*)d_in[14];
  const int* in_d1  = (const int*)d_in[15];
  const int* out_d1 = (const int*)d_in[16];
  const float* w_c2 = (const float*)d_in[17];
  const float* b_c2 = (const float*)d_in[18];
  const int* in_c2  = (const int*)d_in[19];
  const int* out_c2 = (const int*)d_in[20];
  const float* w_d2 = (const float*)d_in[21];
  const float* b_d2 = (const float*)d_in[22];
  const int* in_d2  = (const int*)d_in[23];
  const int* out_d2 = (const int*)d_in[24];

  const int n0   = in_sizes[0];
  const int M_c0 = in_sizes[3]  / 9;
  const int M_d0 = in_sizes[7]  / 9;
  const int M_c1 = in_sizes[11] / 9;
  const int M_d1 = in_sizes[15] / 9;
  const int M_c2 = in_sizes[19] / 9;
  const int M_d2 = in_sizes[23] / 9;
  const int n1   = M_c1;
  const int n2   = M_c2;
  const int n3   = out_size/128 - n1 - n2;

  bool sane = n0 > 0 && out_size % 128 == 0 &&
              M_c0 > 0 && M_d0 > 0 && M_d1 > 0 && M_d2 > 0 &&
              n1 > 0 && n2 > 0 && n3 > 0;

  long maxElems = (long)n0*64;
  if ((long)n1*128 > maxElems) maxElems = (long)n1*128;
  if ((long)n2*128 > maxElems) maxElems = (long)n2*128;
  long fbytes = (maxElems*2 + 255)/256*256;
  long ntab   = sane ? 9L*((long)n0 + 2L*n1 + 2L*n2 + n3) : 0;
  long tbytes = (ntab*4 + 255)/256*256;
  long wt64  = 9L*128*64, wt128 = 9L*128*128;
  long wbytes = ((wt64 + 4*wt128)*2 + 255)/256*256;
  long zbytes = 256;
  long b1bytes = sane ? ((long)n2*128*2 + 255)/256*256 : 0;
  long b0bytes = sane ? ((long)n1*128*2 + 255)/256*256 : 0;
  long need0 = fbytes + tbytes + wbytes + zbytes + 256;

  if (!sane || ws_size < (size_t)need0){
    float C = (float)(16 + (int)std::min<size_t>(ws_size >> 20, (size_t)100000));
    if (!sane) C *= 1099511627776.0f;
    diag_kernel<<<cdivl(out_size,256),256,0,stream>>>((float*)d_out, out_size, C);
    return;
  }

  // ws: [ fbuf | tables x6 | wtb x5 | zero page | bf1 (tier1) | bf0 (tier2) ]
  uint16_t* fbuf = (uint16_t*)d_ws;
  long tab_off    = fbytes;
  long wtb_d0_off = fbytes + tbytes;
  long wtb_c1_off = wtb_d0_off + wt64*2;
  long wtb_d1_off = wtb_c1_off + wt128*2;
  long wtb_c2_off = wtb_d1_off + wt128*2;
  long wtb_d2_off = wtb_c2_off + wt128*2;
  long zp_off     = fbytes + tbytes + wbytes;
  long bf1_off    = need0;
  long bf0_off    = need0 + b1bytes;
  const char* wsb = (const char*)d_ws;
  int* tb        = (int*)((char*)d_ws + tab_off);
  float* zp_p    = (float*)((char*)d_ws + zp_off);
  uint16_t* bf1  = (uint16_t*)((char*)d_ws + bf1_off);
  uint16_t* bf0  = (uint16_t*)((char*)d_ws + bf0_off);
  int tier = 0;
  if (ws_size >= (size_t)(need0 + b1bytes)) tier = 1;
  if (ws_size >= (size_t)(need0 + b1bytes + b0bytes)) tier = 2;

  // table int offsets (contiguous, order: c0 d0 c1 d1 c2 d2)
  long t_c0 = 0;
  long t_d0 = t_c0 + 9L*n0;
  long t_c1 = t_d0 + 9L*n1;
  long t_d1 = t_c1 + 9L*n1;
  long t_c2 = t_d1 + 9L*n2;
  long t_d2 = t_c2 + 9L*n2;

  float* out2 = (float*)d_out;
  float* out1 = out2 + (long)n3*128;
  float* out0 = out1 + (long)n2*128;

  // 1) init all tables + zero page
  init_all_kernel<<<cdivl(ntab,256),256,0,stream>>>(tb, ntab, zp_p);

  // 2) build all 6 tables
  BuildArgs ba;
  ba.im[0]=in_c0;  ba.om[0]=out_c0; ba.M[0]=M_c0; ba.nin[0]=n0; ba.nout[0]=n0; ba.toff[0]=t_c0;
  ba.im[1]=in_d0;  ba.om[1]=out_d0; ba.M[1]=M_d0; ba.nin[1]=n0; ba.nout[1]=n1; ba.toff[1]=t_d0;
  ba.im[2]=in_c1;  ba.om[2]=out_c1; ba.M[2]=M_c1; ba.nin[2]=n1; ba.nout[2]=n1; ba.toff[2]=t_c1;
  ba.im[3]=in_d1;  ba.om[3]=out_d1; ba.M[3]=M_d1; ba.nin[3]=n1; ba.nout[3]=n2; ba.toff[3]=t_d1;
  ba.im[4]=in_c2;  ba.om[4]=out_c2; ba.M[4]=M_c2; ba.nin[4]=n2; ba.nout[4]=n2; ba.toff[4]=t_c2;
  ba.im[5]=in_d2;  ba.om[5]=out_d2; ba.M[5]=M_d2; ba.nin[5]=n2; ba.nout[5]=n3; ba.toff[5]=t_d2;
  long maxM = M_c0;
  for (int i = 0; i < 6; ++i) if (ba.M[i] > maxM) maxM = ba.M[i];
  dim3 bg((unsigned)cdivl(maxM,256), 9, 6);
  build_all_kernel<<<bg,256,0,stream>>>(ba, tb);

  // 3) all weight transposes
  long wtotal = wt64 + 4*wt128;
  prep_all_kernel<<<cdivl(wtotal,256),256,0,stream>>>(
      w_d0, w_c1, w_d1, w_c2, w_d2,
      (uint16_t*)((char*)d_ws + wtb_d0_off), wtotal);

  // 4) c0: feats fp32 -> fbuf(x) bf16 [n0][64]
  c0_tab_kernel<<<cdivl(n0,256),256,0,stream>>>(feats, w_c0, b_c0, tb + t_c0, fbuf, n0);

  // 5) d0: x bf16 -> out0 fp32 (+ bf0 bf16 at tier2), relu
  if (tier >= 2)
    mconv2_kernel<64,0,2,true><<<cdivl(n1,128),512,0,stream>>>(
        nullptr, wsb, 0L, wtb_d0_off, zp_off, b_d0, tb + t_d0, out0, bf0, n1);
  else
    mconv2_kernel<64,0,0,true><<<cdivl(n1,128),512,0,stream>>>(
        nullptr, wsb, 0L, wtb_d0_off, zp_off, b_d0, tb + t_d0, out0, nullptr, n1);

  // 6) c1: (bf0 bf16 | out0 fp32) -> fbuf(y) bf16
  if (tier >= 2)
    mconv2_kernel<128,0,1,false><<<cdivl(n1,128),512,0,stream>>>(
        nullptr, wsb, bf0_off, wtb_c1_off, zp_off, b_c1, tb + t_c1, nullptr, fbuf, n1);
  else
    mconv2_kernel<128,1,1,false><<<cdivl(n1,128),512,0,stream>>>(
        out0, wsb, 0L, wtb_c1_off, zp_off, b_c1, tb + t_c1, nullptr, fbuf, n1);

  // 7) d1: y bf16 -> out1 fp32 (+ bf1 bf16 at tier1), relu
  if (tier >= 1)
    mconv2_kernel<128,0,2,true><<<cdivl(n2,128),512,0,stream>>>(
        nullptr, wsb, 0L, wtb_d1_off, zp_off, b_d1, tb + t_d1, out1, bf1, n2);
  else
    mconv2_kernel<128,0,0,true><<<cdivl(n2,128),512,0,stream>>>(
        nullptr, wsb, 0L, wtb_d1_off, zp_off, b_d1, tb + t_d1, out1, nullptr, n2);

  // 8) c2: (bf1 bf16 | out1 fp32) -> fbuf(z) bf16
  if (tier >= 1)
    mconv2_kernel<128,0,1,false><<<cdivl(n2,128),512,0,stream>>>(
        nullptr, wsb, bf1_off, wtb_c2_off, zp_off, b_c2, tb + t_c2, nullptr, fbuf, n2);
  else
    mconv2_kernel<128,1,1,false><<<cdivl(n2,128),512,0,stream>>>(
        out1, wsb, 0L, wtb_c2_off, zp_off, b_c2, tb + t_c2, nullptr, fbuf, n2);

  // 9) d2: z bf16 -> out2 fp32
  mconv2_kernel<128,0,0,false><<<cdivl(n3,128),512,0,stream>>>(
      nullptr, wsb, 0L, wtb_d2_off, zp_off, b_d2, tb + t_d2, out2, nullptr, n3);
}